// Round 16
// baseline (309.383 us; speedup 1.0000x reference)
//
#include <hip/hip_runtime.h>
#include <math.h>

#define HID   1024
#define STT   4096
#define MTOK  4096   // B*L
#define LSEQ  2048
#define NCHUNK 64
#define CHUNK  32
#define VOCAB  62

typedef __attribute__((ext_vector_type(8))) short short8v;
typedef __attribute__((ext_vector_type(4))) float float4v;

typedef const __attribute__((address_space(1))) void* gptr_t;
typedef __attribute__((address_space(3))) void* lptr_t;

__device__ __forceinline__ float sigmoidf_(float x) {
    return 1.0f / (1.0f + __expf(-x));
}
__device__ __forceinline__ unsigned short f2bf(float f) {
    unsigned int u = __float_as_uint(f);
    unsigned int r = (u + 0x7fffu + ((u >> 16) & 1u)) >> 16;
    return (unsigned short)r;
}
__device__ __forceinline__ float bf2f(unsigned short b) {
    return __uint_as_float(((unsigned int)b) << 16);
}

// ---------------- cast + transpose: src[R][C] f32 -> dst[C][R] bf16 ----------
__global__ __launch_bounds__(256) void cast_transpose_kernel(
    const float* __restrict__ src, unsigned short* __restrict__ dst, int R, int C)
{
    __shared__ float tile[32][33];
    int c0 = blockIdx.x * 32, r0 = blockIdx.y * 32;
    int t = threadIdx.x;
    int r = t >> 3, c4 = (t & 7) << 2;
    float4 v = *(const float4*)(src + (size_t)(r0 + r) * C + c0 + c4);
    tile[r][c4 + 0] = v.x; tile[r][c4 + 1] = v.y;
    tile[r][c4 + 2] = v.z; tile[r][c4 + 3] = v.w;
    __syncthreads();
    int oc = t >> 3;
    int orr = (t & 7) << 2;
    ushort4 o;
    o.x = f2bf(tile[orr + 0][oc]); o.y = f2bf(tile[orr + 1][oc]);
    o.z = f2bf(tile[orr + 2][oc]); o.w = f2bf(tile[orr + 3][oc]);
    *(ushort4*)(dst + (size_t)(c0 + oc) * R + r0 + orr) = o;
}

// ---------------- embedding gather + RMSNorm -> bf16 ----------------
__global__ __launch_bounds__(256) void embed_norm_kernel(
    const int* __restrict__ tokens, const float* __restrict__ embed_w,
    const float* __restrict__ norm_w, unsigned short* __restrict__ xn)
{
    int m = blockIdx.x;
    int t = threadIdx.x;
    int tok = tokens[m];
    float4 x = ((const float4*)(embed_w + (size_t)tok * HID))[t];
    float ss = x.x * x.x + x.y * x.y + x.z * x.z + x.w * x.w;
    for (int off = 32; off > 0; off >>= 1) ss += __shfl_down(ss, off);
    __shared__ float wsum[4];
    if ((t & 63) == 0) wsum[t >> 6] = ss;
    __syncthreads();
    float tot = wsum[0] + wsum[1] + wsum[2] + wsum[3];
    float scale = rsqrtf(tot / (float)HID + 1e-6f);
    float4 w4 = ((const float4*)norm_w)[t];
    ushort4 o;
    o.x = f2bf(x.x * scale * w4.x); o.y = f2bf(x.y * scale * w4.y);
    o.z = f2bf(x.z * scale * w4.z); o.w = f2bf(x.w * scale * w4.w);
    *(ushort4*)(xn + (size_t)m * HID + (t << 2)) = o;
}

// ---------------- merged prologue: W2T (blocks 0..1023) + E_head (1024..1086)
__global__ __launch_bounds__(256) void prep_kernel(
    const float* __restrict__ out_w, const float* __restrict__ head_w,
    const float* __restrict__ embed_w, const float* __restrict__ out_b,
    const float* __restrict__ head_b,
    unsigned short* __restrict__ W2T, float* __restrict__ E_head)
{
    __shared__ float red[4][4][64];
    int tid = threadIdx.x;
    int jc = tid >> 6, n = tid & 63;
    bool act = n < VOCAB;
    if (blockIdx.x < 1024) {
        int k0 = blockIdx.x * 4;
        float a[4] = {0.f, 0.f, 0.f, 0.f};
        int j0 = jc * 256;
        const float* w0 = out_w + (size_t)(k0 + 0) * HID;
        const float* w1 = out_w + (size_t)(k0 + 1) * HID;
        const float* w2 = out_w + (size_t)(k0 + 2) * HID;
        const float* w3 = out_w + (size_t)(k0 + 3) * HID;
        #pragma unroll 4
        for (int j = j0; j < j0 + 256; j++) {
            float h = act ? head_w[(size_t)j * VOCAB + n] : 0.f;
            a[0] = fmaf(w0[j], h, a[0]);
            a[1] = fmaf(w1[j], h, a[1]);
            a[2] = fmaf(w2[j], h, a[2]);
            a[3] = fmaf(w3[j], h, a[3]);
        }
        #pragma unroll
        for (int i = 0; i < 4; i++) red[jc][i][n] = a[i];
        __syncthreads();
        if (jc == 0) {
            #pragma unroll
            for (int i = 0; i < 4; i++) {
                float s = red[0][i][n] + red[1][i][n] + red[2][i][n] + red[3][i][n];
                W2T[(size_t)n * STT + k0 + i] = f2bf(s);
            }
        }
    } else {
        int t = blockIdx.x - 1024;         // 0..62 (62 = bias2 row)
        const float* src = (t < VOCAB) ? (embed_w + (size_t)t * HID) : out_b;
        float acc = 0.f;
        if (act) {
            int j0 = jc * 256;
            #pragma unroll 4
            for (int j = j0; j < j0 + 256; j++)
                acc = fmaf(src[j], head_w[(size_t)j * VOCAB + n], acc);
        }
        red[jc][0][n] = acc;
        __syncthreads();
        if (tid < 64) {
            float s = red[0][0][n] + red[1][0][n] + red[2][0][n] + red[3][0][n];
            if (t == VOCAB && act) s += head_b[n];
            E_head[t * 64 + n] = s;
        }
    }
}

// ---------------- MFMA GEMM 1 + fused gates — m97 structure ----------------
// 128 rows x (4 gates x 32 s), BK=32, 4 waves (4x1 m-split, wave spans full N),
// single 16 KiB LDS buffer, 2-barrier K-loop, gload_lds w16.
// ~3 blocks/CU (implicit cross-block overlap = m97's 912-TF mechanism).
// LDS chunks p = row*4 + (ks^((row>>1)&3)): staging coalesced (16 rows x 64B
// per instr), frag reads 2-way bank = conflict-free (verified rounds 5-15).
// Wave-local gates: acc[mf][nf], gate g = nf>>1, s = s0+(nf&1)*16+lr.
__global__ __launch_bounds__(256) void gemm_in_mfma(
    const unsigned short* __restrict__ A, const unsigned short* __restrict__ B,
    const float* __restrict__ bias,
    unsigned short* __restrict__ a_out, unsigned short* __restrict__ bx_out,
    unsigned short* __restrict__ c_out)
{
    __shared__ __align__(16) unsigned short lds[8192];   // A[4096] B[4096]
    int tid = threadIdx.x;
    int wid = tid >> 6, lane = tid & 63;
    // XCD 2D cells: xcd = (by-half 0..1) x (slab-quarter 0..3); by-fast order
    int wg = blockIdx.x;                   // 4096 = 32 by x 128 slabs
    int xcd = wg & 7, loc = wg >> 3;       // loc 0..511
    int by = (xcd >> 2) * 16 + (loc & 15);       // 0..31
    int slab = (xcd & 3) * 32 + (loc >> 4);      // 0..127
    int m0 = by * 128, s0 = slab * 32;
    int lr = lane & 15, lk = lane >> 4;

    int cb0 = wid * 64, cb1 = 256 + wid * 64;    // wave-uniform chunk bases
    int p0 = cb0 + lane, p1 = cb1 + lane;
    int r0 = p0 >> 2, k0s = (p0 & 3) ^ ((r0 >> 1) & 3);
    int r1 = p1 >> 2, k1s = (p1 & 3) ^ ((r1 >> 1) & 3);
    int arow0 = m0 + r0, arow1 = m0 + r1;
    int bcol0 = ((r0 >> 5) << 12) + s0 + (r0 & 31);
    int bcol1 = ((r1 >> 5) << 12) + s0 + (r1 & 31);

#define STAGE(kt) do {                                                           \
    __builtin_amdgcn_global_load_lds(                                            \
        (gptr_t)(const void*)(A + (size_t)arow0 * 1024 + (kt) * 32 + k0s * 8),   \
        (lptr_t)(void*)(lds + cb0 * 8), 16, 0, 0);                               \
    __builtin_amdgcn_global_load_lds(                                            \
        (gptr_t)(const void*)(A + (size_t)arow1 * 1024 + (kt) * 32 + k1s * 8),   \
        (lptr_t)(void*)(lds + cb1 * 8), 16, 0, 0);                               \
    __builtin_amdgcn_global_load_lds(                                            \
        (gptr_t)(const void*)(B + (size_t)bcol0 * 1024 + (kt) * 32 + k0s * 8),   \
        (lptr_t)(void*)(lds + 4096 + cb0 * 8), 16, 0, 0);                        \
    __builtin_amdgcn_global_load_lds(                                            \
        (gptr_t)(const void*)(B + (size_t)bcol1 * 1024 + (kt) * 32 + k1s * 8),   \
        (lptr_t)(void*)(lds + 4096 + cb1 * 8), 16, 0, 0);                        \
} while (0)

    int ksw = lk ^ ((lr >> 1) & 3);

    float4v acc[2][8];
    float4v z = {0.f, 0.f, 0.f, 0.f};
    #pragma unroll
    for (int i = 0; i < 2; i++)
        #pragma unroll
        for (int j = 0; j < 8; j++) acc[i][j] = z;

    for (int kt = 0; kt < 32; ++kt) {
        STAGE(kt);
        asm volatile("s_waitcnt vmcnt(0)" ::: "memory");
        __builtin_amdgcn_s_barrier();
        short8v af0 = *(const short8v*)&lds[(((wid * 32 + lr) << 2) + ksw) * 8];
        short8v af1 = *(const short8v*)&lds[(((wid * 32 + 16 + lr) << 2) + ksw) * 8];
        short8v bf[8];
        #pragma unroll
        for (int nf = 0; nf < 8; nf++)
            bf[nf] = *(const short8v*)&lds[4096 + (((nf * 16 + lr) << 2) + ksw) * 8];
        __builtin_amdgcn_s_setprio(1);
        #pragma unroll
        for (int nf = 0; nf < 8; nf++) {
            acc[0][nf] = __builtin_amdgcn_mfma_f32_16x16x32_bf16(af0, bf[nf], acc[0][nf], 0, 0, 0);
            acc[1][nf] = __builtin_amdgcn_mfma_f32_16x16x32_bf16(af1, bf[nf], acc[1][nf], 0, 0, 0);
        }
        __builtin_amdgcn_s_setprio(0);
        asm volatile("" ::: "memory");
        __builtin_amdgcn_s_barrier();
    }
#undef STAGE

    // fused-gate epilogue: thread holds all 4 gates for s = s0+h*16+lr
    float b_xg[2], b_a[2], b_b[2], b_c[2];
    #pragma unroll
    for (int h = 0; h < 2; h++) {
        int s = s0 + h * 16 + lr;
        b_xg[h] = bias[s];
        b_a[h]  = bias[4096 + s];
        b_b[h]  = bias[8192 + s];
        b_c[h]  = bias[12288 + s];
    }
    int rbase = lk << 2;
    #pragma unroll
    for (int mf = 0; mf < 2; mf++)
        #pragma unroll
        for (int q = 0; q < 4; q++) {
            int m = m0 + wid * 32 + mf * 16 + rbase + q;
            #pragma unroll
            for (int h = 0; h < 2; h++) {
                int s = s0 + h * 16 + lr;
                size_t idx = (size_t)m * STT + s;
                float xg = acc[mf][0 + h][q] + b_xg[h];
                float a  = sigmoidf_(acc[mf][2 + h][q] + b_a[h]);
                float bxv = sigmoidf_(acc[mf][4 + h][q] + b_b[h]) * xg;
                float c  = sigmoidf_(acc[mf][6 + h][q] + b_c[h]);
                a_out[idx]  = f2bf(a);
                bx_out[idx] = f2bf(bxv);
                c_out[idx]  = f2bf(c);
            }
        }
}

// ---------------- logits GEMM: part[s] = y[mtile] @ W2T^T (K-slice) --------
__global__ __launch_bounds__(256, 3) void logits_gemm(
    const unsigned short* __restrict__ Y, const unsigned short* __restrict__ W2T,
    float* __restrict__ part)
{
    extern __shared__ unsigned short lds[];   // 3 bufs * 6144 shorts = 36 KiB
    int tid = threadIdx.x;
    int wid = tid >> 6, lane = tid & 63;
    int wg = blockIdx.x;
    int m0 = (wg & 31) * 128;
    int slice = wg >> 5;
    int ks0 = slice * 512;
    int wm = wid >> 1, wn = wid & 1;
    int lr = lane & 15, lk = lane >> 4;

    auto stage = [&](int b, int kt) {
        unsigned short* As = lds + b * 6144;
        unsigned short* Bs = As + 4096;
        #pragma unroll
        for (int i = 0; i < 2; i++) {
            int cb = i * 256 + wid * 64;
            int p = cb + lane;
            int row = p >> 2;
            int ks = (p & 3) ^ ((row >> 1) & 3);
            __builtin_amdgcn_global_load_lds(
                (gptr_t)(const void*)(Y + (size_t)(m0 + row) * STT + kt + ks * 8),
                (lptr_t)(void*)(As + (size_t)cb * 8), 16, 0, 0);
        }
        {
            int cb = wid * 64;
            int p = cb + lane;
            int row = p >> 2;
            int ks = (p & 3) ^ ((row >> 1) & 3);
            __builtin_amdgcn_global_load_lds(
                (gptr_t)(const void*)(W2T + (size_t)row * STT + kt + ks * 8),
                (lptr_t)(void*)(Bs + (size_t)cb * 8), 16, 0, 0);
        }
    };

    float4v acc[4][2];
    float4v z = {0.f, 0.f, 0.f, 0.f};
    #pragma unroll
    for (int i = 0; i < 4; i++) { acc[i][0] = z; acc[i][1] = z; }

    const int nt = 16;
    stage(0, ks0); stage(1, ks0 + 32);

    int ksw = lk ^ ((lr >> 1) & 3);

    for (int t = 0; t < nt; ++t) {
        if (t + 2 < nt) stage((t + 2) % 3, ks0 + (t + 2) * 32);
        if (t + 2 < nt)      asm volatile("s_waitcnt vmcnt(6)" ::: "memory");
        else if (t + 1 < nt) asm volatile("s_waitcnt vmcnt(3)" ::: "memory");
        else                 asm volatile("s_waitcnt vmcnt(0)" ::: "memory");
        __builtin_amdgcn_s_barrier();
        asm volatile("" ::: "memory");
        const unsigned short* As = lds + (t % 3) * 6144;
        const unsigned short* Bs = As + 4096;
        short8v af[4], bfr[2];
        #pragma unroll
        for (int f = 0; f < 4; f++)
            af[f] = *(const short8v*)&As[(((wm * 64 + f * 16 + lr) << 2) + ksw) * 8];
        #pragma unroll
        for (int g = 0; g < 2; g++)
            bfr[g] = *(const short8v*)&Bs[(((wn * 32 + g * 16 + lr) << 2) + ksw) * 8];
        __builtin_amdgcn_s_setprio(1);
        #pragma unroll
        for (int f = 0; f < 4; f++)
            #pragma unroll
            for (int g = 0; g < 2; g++)
                acc[f][g] = __builtin_amdgcn_mfma_f32_16x16x32_bf16(
                    af[f], bfr[g], acc[f][g], 0, 0, 0);
        __builtin_amdgcn_s_setprio(0);
        asm volatile("" ::: "memory");
        __builtin_amdgcn_s_barrier();
    }

    float* pb = part + (size_t)slice * MTOK * 64;
    int rbase = lk << 2;
    #pragma unroll
    for (int f = 0; f < 4; f++)
        #pragma unroll
        for (int g = 0; g < 2; g++) {
            int n = wn * 32 + g * 16 + lr;
            #pragma unroll
            for (int q = 0; q < 4; q++) {
                int m = m0 + wm * 64 + f * 16 + rbase + q;
                pb[(size_t)m * 64 + n] = acc[f][g][q];
            }
        }
}

// ---------------- logits reduce: sum 8 partials + E_head[tok] + bias2 -------
__global__ __launch_bounds__(64) void logits_reduce(
    const float* __restrict__ part, const float* __restrict__ E_head,
    const int* __restrict__ tokens, float* __restrict__ logits)
{
    int m = blockIdx.x;
    int n = threadIdx.x;
    if (n >= VOCAB) return;
    int tok = tokens[m];
    float s = E_head[tok * 64 + n] + E_head[VOCAB * 64 + n];
    #pragma unroll
    for (int sl = 0; sl < 8; sl++)
        s += part[(size_t)sl * MTOK * 64 + (size_t)m * 64 + n];
    logits[(size_t)m * VOCAB + n] = s;
}

// ---------------- scan phase 1 (frozen) ----------
__global__ __launch_bounds__(256) void scan_phase1(
    const unsigned short* __restrict__ a_buf, const unsigned short* __restrict__ bx_buf,
    float* __restrict__ chunkA, float* __restrict__ chunkH)
{
    int bid = blockIdx.x;
    int sg = bid & 3, q = (bid >> 2) & 63, b = bid >> 8;
    int s0 = sg * 1024 + threadIdx.x * 4;
    size_t base = (size_t)(b * LSEQ + q * CHUNK) * STT + s0;
    const unsigned short* ap = a_buf + base;
    const unsigned short* bp = bx_buf + base;
    float Aa[4] = {1.f, 1.f, 1.f, 1.f}, Hh[4] = {0.f, 0.f, 0.f, 0.f};
    for (int t = 0; t < CHUNK; t++) {
        ushort4 Av = *(const ushort4*)ap;
        ushort4 Bv = *(const ushort4*)bp;
        const unsigned short* avp = (const unsigned short*)&Av;
        const unsigned short* bvp = (const unsigned short*)&Bv;
        #pragma unroll
        for (int j = 0; j < 4; j++) {
            float a = bf2f(avp[j]);
            Hh[j] = fmaf(a, Hh[j], bf2f(bvp[j]));
            Aa[j] *= a;
        }
        ap += STT; bp += STT;
    }
    #pragma unroll
    for (int j = 0; j < 4; j++) {
        int ch = b * STT + s0 + j;
        chunkA[ch * NCHUNK + q] = Aa[j];
        chunkH[ch * NCHUNK + q] = Hh[j];
    }
}

__global__ __launch_bounds__(256) void scan_phase2(
    const float* __restrict__ chunkA, const float* __restrict__ chunkH,
    float* __restrict__ carry)
{
    int ch = blockIdx.x * 256 + threadIdx.x;
    float c = 0.f;
    for (int q = 0; q < NCHUNK; q++) {
        carry[ch * NCHUNK + q] = c;
        c = fmaf(chunkA[ch * NCHUNK + q], c, chunkH[ch * NCHUNK + q]);
    }
}

// ---------------- scan phase 3 (frozen) ----------
__global__ __launch_bounds__(256) void scan_phase3(
    const unsigned short* __restrict__ a_buf, const unsigned short* __restrict__ bx_buf,
    const unsigned short* __restrict__ c_buf, const float* __restrict__ carry,
    unsigned short* __restrict__ y)
{
    int bid = blockIdx.x;
    int sg = bid & 3, q = (bid >> 2) & 63, b = bid >> 8;
    int s0 = sg * 1024 + threadIdx.x * 4;
    float h[4];
    #pragma unroll
    for (int j = 0; j < 4; j++)
        h[j] = carry[(b * STT + s0 + j) * NCHUNK + q];
    size_t base = (size_t)(b * LSEQ + q * CHUNK) * STT + s0;
    const unsigned short* ap = a_buf + base;
    const unsigned short* bp = bx_buf + base;
    const unsigned short* cp = c_buf + base;
    unsigned short* yp = y + base;
    for (int t = 0; t < CHUNK; t++) {
        ushort4 Av = *(const ushort4*)ap;
        ushort4 Bv = *(const ushort4*)bp;
        ushort4 Cv = *(const ushort4*)cp;
        const unsigned short* avp = (const unsigned short*)&Av;
        const unsigned short* bvp = (const unsigned short*)&Bv;
        const unsigned short* cvp = (const unsigned short*)&Cv;
        ushort4 o;
        unsigned short* op = (unsigned short*)&o;
        #pragma unroll
        for (int j = 0; j < 4; j++) {
            h[j] = fmaf(bf2f(avp[j]), h[j], bf2f(bvp[j]));
            op[j] = f2bf(bf2f(cvp[j]) * h[j]);
        }
        *(ushort4*)yp = o;
        ap += STT; bp += STT; cp += STT; yp += STT;
    }
}

extern "C" void kernel_launch(void* const* d_in, const int* in_sizes, int n_in,
                              void* d_out, int out_size, void* d_ws, size_t ws_size,
                              hipStream_t stream) {
    const int*   tokens  = (const int*)d_in[0];
    const float* embed_w = (const float*)d_in[1];
    const float* norm_w  = (const float*)d_in[2];
    const float* in_w    = (const float*)d_in[3];
    const float* in_b    = (const float*)d_in[4];
    const float* out_w   = (const float*)d_in[5];
    const float* out_b   = (const float*)d_in[6];
    const float* head_w  = (const float*)d_in[7];
    const float* head_b  = (const float*)d_in[8];
    float* logits = (float*)d_out;

    char* w = (char*)d_ws;
    unsigned short* a_buf  = (unsigned short*)w;                    // 32 MiB
    unsigned short* bx_buf = (unsigned short*)(w + 33554432);       // 32 MiB
    unsigned short* c_buf  = (unsigned short*)(w + 67108864);       // 32 MiB
    unsigned short* W2T    = (unsigned short*)(w + 100663296);      // 512 KiB
    float*          E_head = (float*)(w + 101711872);               // 16 KiB
    float*          part   = (float*)(w + 102760448);               // 8 MiB
    unsigned short* y      = (unsigned short*)(w + 134217728);      // 32 MiB
    unsigned short* in_wT  = (unsigned short*)(w + 167772160);      // 32 MiB
    unsigned short* xn     = (unsigned short*)(w + 201326592);      // 8 MiB
    float* chunkA = (float*)(w + 209715200);
    float* chunkH = chunkA + 8192 * NCHUNK;
    float* carry  = chunkH + 8192 * NCHUNK;

    hipLaunchKernelGGL(cast_transpose_kernel, dim3(16384 / 32, 1024 / 32), dim3(256), 0, stream,
                       in_w, in_wT, 1024, 16384);
    hipLaunchKernelGGL(embed_norm_kernel, dim3(MTOK), dim3(256), 0, stream,
                       tokens, embed_w, norm_w, xn);
    hipLaunchKernelGGL(prep_kernel, dim3(1024 + VOCAB + 1), dim3(256), 0, stream,
                       out_w, head_w, embed_w, out_b, head_b, W2T, E_head);
    hipLaunchKernelGGL(gemm_in_mfma, dim3(4096), dim3(256), 0, stream,
                       xn, in_wT, in_b, a_buf, bx_buf, c_buf);
    hipLaunchKernelGGL(scan_phase1, dim3(512), dim3(256), 0, stream,
                       a_buf, bx_buf, chunkA, chunkH);
    hipLaunchKernelGGL(scan_phase2, dim3(32), dim3(256), 0, stream,
                       chunkA, chunkH, carry);
    hipLaunchKernelGGL(scan_phase3, dim3(512), dim3(256), 0, stream,
                       a_buf, bx_buf, c_buf, carry, y);
    hipLaunchKernelGGL(logits_gemm, dim3(256), dim3(256), 36864, stream,
                       y, W2T, part);
    hipLaunchKernelGGL(logits_reduce, dim3(MTOK), dim3(64), 0, stream,
                       part, E_head, tokens, logits);
}

// Round 18
// 288.292 us; speedup vs baseline: 1.0732x; 1.0732x over previous
//
#include <hip/hip_runtime.h>
#include <math.h>

#define HID   1024
#define STT   4096
#define MTOK  4096   // B*L
#define LSEQ  2048
#define NCHUNK 64
#define CHUNK  32
#define VOCAB  62

typedef __attribute__((ext_vector_type(8))) short short8v;
typedef __attribute__((ext_vector_type(4))) float float4v;

typedef const __attribute__((address_space(1))) void* gptr_t;
typedef __attribute__((address_space(3))) void* lptr_t;

__device__ __forceinline__ float sigmoidf_(float x) {
    return 1.0f / (1.0f + __expf(-x));
}
__device__ __forceinline__ unsigned short f2bf(float f) {
    unsigned int u = __float_as_uint(f);
    unsigned int r = (u + 0x7fffu + ((u >> 16) & 1u)) >> 16;
    return (unsigned short)r;
}
__device__ __forceinline__ float bf2f(unsigned short b) {
    return __uint_as_float(((unsigned int)b) << 16);
}

// ---------------- fused prologue (block-range partitioned) ----------------
// blocks 0..16383      : in_w [1024][16384] -> in_wT [16384][1024] bf16
// blocks 16384..20479  : embed gather + RMSNorm -> xn bf16
// blocks 20480..21503  : W2T = (out_w@head_w)^T bf16 [64][4096]
// blocks 21504..21566  : E_head rows (62 embed rows + bias2 row)
__global__ __launch_bounds__(256) void fused_pre(
    const int* __restrict__ tokens, const float* __restrict__ embed_w,
    const float* __restrict__ norm_w, const float* __restrict__ in_w,
    const float* __restrict__ out_w, const float* __restrict__ head_w,
    const float* __restrict__ out_b, const float* __restrict__ head_b,
    unsigned short* __restrict__ in_wT, unsigned short* __restrict__ xn,
    unsigned short* __restrict__ W2T, float* __restrict__ E_head)
{
    __shared__ float sh[1056];   // transpose tile 32x33 / red[4][4][64] overlay
    int bid = blockIdx.x;
    int tid = threadIdx.x;
    if (bid < 16384) {
        // ---- transpose: bx = bid & 511 (col tile), by = bid >> 9 (row tile)
        float (*tile)[33] = (float (*)[33])sh;
        int c0 = (bid & 511) * 32, r0 = (bid >> 9) * 32;
        int r = tid >> 3, c4 = (tid & 7) << 2;
        float4 v = *(const float4*)(in_w + (size_t)(r0 + r) * 16384 + c0 + c4);
        tile[r][c4 + 0] = v.x; tile[r][c4 + 1] = v.y;
        tile[r][c4 + 2] = v.z; tile[r][c4 + 3] = v.w;
        __syncthreads();
        int oc = tid >> 3;
        int orr = (tid & 7) << 2;
        ushort4 o;
        o.x = f2bf(tile[orr + 0][oc]); o.y = f2bf(tile[orr + 1][oc]);
        o.z = f2bf(tile[orr + 2][oc]); o.w = f2bf(tile[orr + 3][oc]);
        *(ushort4*)(in_wT + (size_t)(c0 + oc) * 1024 + r0 + orr) = o;
    } else if (bid < 20480) {
        // ---- embed + RMSNorm
        int m = bid - 16384;
        int tok = tokens[m];
        float4 x = ((const float4*)(embed_w + (size_t)tok * HID))[tid];
        float ss = x.x * x.x + x.y * x.y + x.z * x.z + x.w * x.w;
        for (int off = 32; off > 0; off >>= 1) ss += __shfl_down(ss, off);
        if ((tid & 63) == 0) sh[tid >> 6] = ss;
        __syncthreads();
        float tot = sh[0] + sh[1] + sh[2] + sh[3];
        float scale = rsqrtf(tot / (float)HID + 1e-6f);
        float4 w4 = ((const float4*)norm_w)[tid];
        ushort4 o;
        o.x = f2bf(x.x * scale * w4.x); o.y = f2bf(x.y * scale * w4.y);
        o.z = f2bf(x.z * scale * w4.z); o.w = f2bf(x.w * scale * w4.w);
        *(ushort4*)(xn + (size_t)m * HID + (tid << 2)) = o;
    } else if (bid < 21504) {
        // ---- W2T: block = 4 k-rows, 4-way j-split + LDS reduce
        float (*red)[4][64] = (float (*)[4][64])sh;
        int jc = tid >> 6, n = tid & 63;
        bool act = n < VOCAB;
        int k0 = (bid - 20480) * 4;
        float a[4] = {0.f, 0.f, 0.f, 0.f};
        int j0 = jc * 256;
        const float* w0 = out_w + (size_t)(k0 + 0) * HID;
        const float* w1 = out_w + (size_t)(k0 + 1) * HID;
        const float* w2 = out_w + (size_t)(k0 + 2) * HID;
        const float* w3 = out_w + (size_t)(k0 + 3) * HID;
        #pragma unroll 4
        for (int j = j0; j < j0 + 256; j++) {
            float h = act ? head_w[(size_t)j * VOCAB + n] : 0.f;
            a[0] = fmaf(w0[j], h, a[0]);
            a[1] = fmaf(w1[j], h, a[1]);
            a[2] = fmaf(w2[j], h, a[2]);
            a[3] = fmaf(w3[j], h, a[3]);
        }
        #pragma unroll
        for (int i = 0; i < 4; i++) red[jc][i][n] = a[i];
        __syncthreads();
        if (jc == 0) {
            #pragma unroll
            for (int i = 0; i < 4; i++) {
                float s = red[0][i][n] + red[1][i][n] + red[2][i][n] + red[3][i][n];
                W2T[(size_t)n * STT + k0 + i] = f2bf(s);
            }
        }
    } else {
        // ---- E_head row t (t==VOCAB -> bias2 row from out_b)
        float (*red)[4][64] = (float (*)[4][64])sh;
        int jc = tid >> 6, n = tid & 63;
        bool act = n < VOCAB;
        int t = bid - 21504;
        const float* src = (t < VOCAB) ? (embed_w + (size_t)t * HID) : out_b;
        float acc = 0.f;
        if (act) {
            int j0 = jc * 256;
            #pragma unroll 4
            for (int j = j0; j < j0 + 256; j++)
                acc = fmaf(src[j], head_w[(size_t)j * VOCAB + n], acc);
        }
        red[jc][0][n] = acc;
        __syncthreads();
        if (tid < 64) {
            float s = red[0][0][n] + red[1][0][n] + red[2][0][n] + red[3][0][n];
            if (t == VOCAB && act) s += head_b[n];
            E_head[t * 64 + n] = s;
        }
    }
}

// ---------------- MFMA GEMM 1 + fused gates (round-12/15 version, 187 us) ----
// 256 rows x (4 gates x 64 s-cols), BK=64, 8 waves, 2 LDS bufs, 4-phase
// counted-vmcnt schedule, conflict-free chunk swizzle, XCD cell swizzle.
__global__ __launch_bounds__(512, 2) void gemm_in_mfma(
    const unsigned short* __restrict__ A, const unsigned short* __restrict__ B,
    const float* __restrict__ bias,
    unsigned short* __restrict__ a_out, unsigned short* __restrict__ bx_out,
    unsigned short* __restrict__ c_out)
{
    extern __shared__ unsigned short lds[];   // 2 bufs * 32768 shorts = 128 KiB
    int tid = threadIdx.x;
    int wid = tid >> 6, lane = tid & 63;
    int wg = blockIdx.x;
    int xcd = wg & 7, loc = wg >> 3;
    int by = ((xcd >> 1) << 2) + (loc & 3);   // 0..15  m-tile
    int bx = ((xcd & 1) << 5) + (loc >> 2);   // 0..63  s-slab
    int m0 = by * 256, s0 = bx * 64;
    int wm = wid >> 2, wn = wid & 3;
    int lr = lane & 15, lk = lane >> 4;

    int cb0 = wid * 64, cb1 = 512 + wid * 64;
    int p0 = cb0 + lane, p1 = cb1 + lane;
    int row0 = p0 >> 2, ks0 = (p0 & 3) ^ ((row0 >> 1) & 3);
    int row1 = p1 >> 2, ks1 = (p1 & 3) ^ ((row1 >> 1) & 3);
    int arow0 = m0 + row0, arow1 = m0 + row1;
    int brow0 = ((row0 >> 6) << 12) + s0 + (row0 & 63);
    int brow1 = ((row1 >> 6) << 12) + s0 + (row1 & 63);

#define SHALF(grow0, grow1, b, which, kt, kk) do {                               \
    unsigned short* _d = lds + (b) * 32768 + (which) * 16384 + (kk) * 8192;      \
    __builtin_amdgcn_global_load_lds(                                            \
        (gptr_t)(const void*)(((which) ? B : A) + (size_t)(grow0) * 1024 +       \
                              (kt) * 64 + (kk) * 32 + ks0 * 8),                  \
        (lptr_t)(void*)(_d + (size_t)cb0 * 8), 16, 0, 0);                        \
    __builtin_amdgcn_global_load_lds(                                            \
        (gptr_t)(const void*)(((which) ? B : A) + (size_t)(grow1) * 1024 +       \
                              (kt) * 64 + (kk) * 32 + ks1 * 8),                  \
        (lptr_t)(void*)(_d + (size_t)cb1 * 8), 16, 0, 0);                        \
} while (0)

    int ksw = lk ^ ((lr >> 1) & 3);

#define RD_A(b, kk, mf) \
    (*(const short8v*)&lds[(b) * 32768 + (kk) * 8192 + \
        (((wm * 128 + (mf) * 16 + lr) << 2) + ksw) * 8])
#define RD_B(b, kk, nf) \
    (*(const short8v*)&lds[(b) * 32768 + 16384 + (kk) * 8192 + \
        ((((nf) * 64 + wn * 16 + lr) << 2) + ksw) * 8])

#define MFMA8x2(AF, B0, B1, n0i, n1i) do {                                       \
    __builtin_amdgcn_s_setprio(1);                                               \
    _Pragma("unroll")                                                            \
    for (int mf = 0; mf < 8; mf++) {                                             \
        acc[mf][n0i] = __builtin_amdgcn_mfma_f32_16x16x32_bf16(                  \
            (AF)[mf], (B0), acc[mf][n0i], 0, 0, 0);                              \
        acc[mf][n1i] = __builtin_amdgcn_mfma_f32_16x16x32_bf16(                  \
            (AF)[mf], (B1), acc[mf][n1i], 0, 0, 0);                              \
    }                                                                            \
    __builtin_amdgcn_s_setprio(0);                                               \
} while (0)

#define BAR_IN()  do { __builtin_amdgcn_s_barrier();                              \
    asm volatile("s_waitcnt lgkmcnt(0)" ::: "memory");                           \
    __builtin_amdgcn_sched_barrier(0); } while (0)
#define BAR_OUT() do { asm volatile("" ::: "memory");                             \
    __builtin_amdgcn_s_barrier(); } while (0)

    float4v acc[8][4];
    float4v z = {0.f, 0.f, 0.f, 0.f};
    #pragma unroll
    for (int i = 0; i < 8; i++)
        #pragma unroll
        for (int j = 0; j < 4; j++) acc[i][j] = z;

    SHALF(arow0, arow1, 0, 0, 0, 0); SHALF(brow0, brow1, 0, 1, 0, 0);
    SHALF(arow0, arow1, 0, 0, 0, 1); SHALF(brow0, brow1, 0, 1, 0, 1);
    asm volatile("s_waitcnt vmcnt(0)" ::: "memory");
    __builtin_amdgcn_s_barrier();

    short8v af[8], bf0, bf1;

    for (int kt = 0; kt < 16; ++kt) {
        int cur = kt & 1, nxt = cur ^ 1;
        int ktn = kt < 15 ? kt + 1 : 15;
        #pragma unroll
        for (int mf = 0; mf < 8; mf++) af[mf] = RD_A(cur, 0, mf);
        bf0 = RD_B(cur, 0, 0); bf1 = RD_B(cur, 0, 1);
        asm volatile("s_waitcnt vmcnt(4)" ::: "memory");
        SHALF(arow0, arow1, nxt, 0, ktn, 0);
        BAR_IN();
        MFMA8x2(af, bf0, bf1, 0, 1);
        BAR_OUT();
        bf0 = RD_B(cur, 0, 2); bf1 = RD_B(cur, 0, 3);
        SHALF(brow0, brow1, nxt, 1, ktn, 0);
        BAR_IN();
        MFMA8x2(af, bf0, bf1, 2, 3);
        BAR_OUT();
        #pragma unroll
        for (int mf = 0; mf < 8; mf++) af[mf] = RD_A(cur, 1, mf);
        bf0 = RD_B(cur, 1, 0); bf1 = RD_B(cur, 1, 1);
        asm volatile("s_waitcnt vmcnt(4)" ::: "memory");
        SHALF(arow0, arow1, nxt, 0, ktn, 1);
        BAR_IN();
        MFMA8x2(af, bf0, bf1, 0, 1);
        BAR_OUT();
        bf0 = RD_B(cur, 1, 2); bf1 = RD_B(cur, 1, 3);
        SHALF(brow0, brow1, nxt, 1, ktn, 1);
        BAR_IN();
        MFMA8x2(af, bf0, bf1, 2, 3);
        BAR_OUT();
    }

    int s = s0 + wn * 16 + lr;
    float b_xg = bias[s];
    float b_a  = bias[4096 + s];
    float b_b  = bias[8192 + s];
    float b_c  = bias[12288 + s];
    int rbase = lk << 2;
    #pragma unroll
    for (int mf = 0; mf < 8; mf++)
        #pragma unroll
        for (int q = 0; q < 4; q++) {
            int m = m0 + wm * 128 + mf * 16 + rbase + q;
            size_t idx = (size_t)m * STT + s;
            float xg = acc[mf][0][q] + b_xg;
            float a  = sigmoidf_(acc[mf][1][q] + b_a);
            float bxv = sigmoidf_(acc[mf][2][q] + b_b) * xg;
            float c  = sigmoidf_(acc[mf][3][q] + b_c);
            a_out[idx]  = f2bf(a);
            bx_out[idx] = f2bf(bxv);
            c_out[idx]  = f2bf(c);
        }
#undef SHALF
#undef RD_A
#undef RD_B
#undef MFMA8x2
#undef BAR_IN
#undef BAR_OUT
}

// ---------------- logits GEMM: part[s] = y[mtile] @ W2T^T (K-slice) --------
__global__ __launch_bounds__(256, 3) void logits_gemm(
    const unsigned short* __restrict__ Y, const unsigned short* __restrict__ W2T,
    float* __restrict__ part)
{
    extern __shared__ unsigned short lds[];   // 3 bufs * 6144 shorts = 36 KiB
    int tid = threadIdx.x;
    int wid = tid >> 6, lane = tid & 63;
    int wg = blockIdx.x;
    int m0 = (wg & 31) * 128;
    int slice = wg >> 5;
    int ks0 = slice * 512;
    int wm = wid >> 1, wn = wid & 1;
    int lr = lane & 15, lk = lane >> 4;

    auto stage = [&](int b, int kt) {
        unsigned short* As = lds + b * 6144;
        unsigned short* Bs = As + 4096;
        #pragma unroll
        for (int i = 0; i < 2; i++) {
            int cb = i * 256 + wid * 64;
            int p = cb + lane;
            int row = p >> 2;
            int ks = (p & 3) ^ ((row >> 1) & 3);
            __builtin_amdgcn_global_load_lds(
                (gptr_t)(const void*)(Y + (size_t)(m0 + row) * STT + kt + ks * 8),
                (lptr_t)(void*)(As + (size_t)cb * 8), 16, 0, 0);
        }
        {
            int cb = wid * 64;
            int p = cb + lane;
            int row = p >> 2;
            int ks = (p & 3) ^ ((row >> 1) & 3);
            __builtin_amdgcn_global_load_lds(
                (gptr_t)(const void*)(W2T + (size_t)row * STT + kt + ks * 8),
                (lptr_t)(void*)(Bs + (size_t)cb * 8), 16, 0, 0);
        }
    };

    float4v acc[4][2];
    float4v z = {0.f, 0.f, 0.f, 0.f};
    #pragma unroll
    for (int i = 0; i < 4; i++) { acc[i][0] = z; acc[i][1] = z; }

    const int nt = 16;
    stage(0, ks0); stage(1, ks0 + 32);

    int ksw = lk ^ ((lr >> 1) & 3);

    for (int t = 0; t < nt; ++t) {
        if (t + 2 < nt) stage((t + 2) % 3, ks0 + (t + 2) * 32);
        if (t + 2 < nt)      asm volatile("s_waitcnt vmcnt(6)" ::: "memory");
        else if (t + 1 < nt) asm volatile("s_waitcnt vmcnt(3)" ::: "memory");
        else                 asm volatile("s_waitcnt vmcnt(0)" ::: "memory");
        __builtin_amdgcn_s_barrier();
        asm volatile("" ::: "memory");
        const unsigned short* As = lds + (t % 3) * 6144;
        const unsigned short* Bs = As + 4096;
        short8v af[4], bfr[2];
        #pragma unroll
        for (int f = 0; f < 4; f++)
            af[f] = *(const short8v*)&As[(((wm * 64 + f * 16 + lr) << 2) + ksw) * 8];
        #pragma unroll
        for (int g = 0; g < 2; g++)
            bfr[g] = *(const short8v*)&Bs[(((wn * 32 + g * 16 + lr) << 2) + ksw) * 8];
        __builtin_amdgcn_s_setprio(1);
        #pragma unroll
        for (int f = 0; f < 4; f++)
            #pragma unroll
            for (int g = 0; g < 2; g++)
                acc[f][g] = __builtin_amdgcn_mfma_f32_16x16x32_bf16(
                    af[f], bfr[g], acc[f][g], 0, 0, 0);
        __builtin_amdgcn_s_setprio(0);
        asm volatile("" ::: "memory");
        __builtin_amdgcn_s_barrier();
    }

    float* pb = part + (size_t)slice * MTOK * 64;
    int rbase = lk << 2;
    #pragma unroll
    for (int f = 0; f < 4; f++)
        #pragma unroll
        for (int g = 0; g < 2; g++) {
            int n = wn * 32 + g * 16 + lr;
            #pragma unroll
            for (int q = 0; q < 4; q++) {
                int m = m0 + wm * 64 + f * 16 + rbase + q;
                pb[(size_t)m * 64 + n] = acc[f][g][q];
            }
        }
}

// ---------------- logits reduce: sum 8 partials + E_head[tok] + bias2 -------
__global__ __launch_bounds__(64) void logits_reduce(
    const float* __restrict__ part, const float* __restrict__ E_head,
    const int* __restrict__ tokens, float* __restrict__ logits)
{
    int m = blockIdx.x;
    int n = threadIdx.x;
    if (n >= VOCAB) return;
    int tok = tokens[m];
    float s = E_head[tok * 64 + n] + E_head[VOCAB * 64 + n];
    #pragma unroll
    for (int sl = 0; sl < 8; sl++)
        s += part[(size_t)sl * MTOK * 64 + (size_t)m * 64 + n];
    logits[(size_t)m * VOCAB + n] = s;
}

// ---------------- scan phase 1 (frozen) ----------
__global__ __launch_bounds__(256) void scan_phase1(
    const unsigned short* __restrict__ a_buf, const unsigned short* __restrict__ bx_buf,
    float* __restrict__ chunkA, float* __restrict__ chunkH)
{
    int bid = blockIdx.x;
    int sg = bid & 3, q = (bid >> 2) & 63, b = bid >> 8;
    int s0 = sg * 1024 + threadIdx.x * 4;
    size_t base = (size_t)(b * LSEQ + q * CHUNK) * STT + s0;
    const unsigned short* ap = a_buf + base;
    const unsigned short* bp = bx_buf + base;
    float Aa[4] = {1.f, 1.f, 1.f, 1.f}, Hh[4] = {0.f, 0.f, 0.f, 0.f};
    for (int t = 0; t < CHUNK; t++) {
        ushort4 Av = *(const ushort4*)ap;
        ushort4 Bv = *(const ushort4*)bp;
        const unsigned short* avp = (const unsigned short*)&Av;
        const unsigned short* bvp = (const unsigned short*)&Bv;
        #pragma unroll
        for (int j = 0; j < 4; j++) {
            float a = bf2f(avp[j]);
            Hh[j] = fmaf(a, Hh[j], bf2f(bvp[j]));
            Aa[j] *= a;
        }
        ap += STT; bp += STT;
    }
    #pragma unroll
    for (int j = 0; j < 4; j++) {
        int ch = b * STT + s0 + j;
        chunkA[ch * NCHUNK + q] = Aa[j];
        chunkH[ch * NCHUNK + q] = Hh[j];
    }
}

__global__ __launch_bounds__(256) void scan_phase2(
    const float* __restrict__ chunkA, const float* __restrict__ chunkH,
    float* __restrict__ carry)
{
    int ch = blockIdx.x * 256 + threadIdx.x;
    float c = 0.f;
    for (int q = 0; q < NCHUNK; q++) {
        carry[ch * NCHUNK + q] = c;
        c = fmaf(chunkA[ch * NCHUNK + q], c, chunkH[ch * NCHUNK + q]);
    }
}

// ---------------- scan phase 3 (frozen) ----------
__global__ __launch_bounds__(256) void scan_phase3(
    const unsigned short* __restrict__ a_buf, const unsigned short* __restrict__ bx_buf,
    const unsigned short* __restrict__ c_buf, const float* __restrict__ carry,
    unsigned short* __restrict__ y)
{
    int bid = blockIdx.x;
    int sg = bid & 3, q = (bid >> 2) & 63, b = bid >> 8;
    int s0 = sg * 1024 + threadIdx.x * 4;
    float h[4];
    #pragma unroll
    for (int j = 0; j < 4; j++)
        h[j] = carry[(b * STT + s0 + j) * NCHUNK + q];
    size_t base = (size_t)(b * LSEQ + q * CHUNK) * STT + s0;
    const unsigned short* ap = a_buf + base;
    const unsigned short* bp = bx_buf + base;
    const unsigned short* cp = c_buf + base;
    unsigned short* yp = y + base;
    for (int t = 0; t < CHUNK; t++) {
        ushort4 Av = *(const ushort4*)ap;
        ushort4 Bv = *(const ushort4*)bp;
        ushort4 Cv = *(const ushort4*)cp;
        const unsigned short* avp = (const unsigned short*)&Av;
        const unsigned short* bvp = (const unsigned short*)&Bv;
        const unsigned short* cvp = (const unsigned short*)&Cv;
        ushort4 o;
        unsigned short* op = (unsigned short*)&o;
        #pragma unroll
        for (int j = 0; j < 4; j++) {
            h[j] = fmaf(bf2f(avp[j]), h[j], bf2f(bvp[j]));
            op[j] = f2bf(bf2f(cvp[j]) * h[j]);
        }
        *(ushort4*)yp = o;
        ap += STT; bp += STT; cp += STT; yp += STT;
    }
}

extern "C" void kernel_launch(void* const* d_in, const int* in_sizes, int n_in,
                              void* d_out, int out_size, void* d_ws, size_t ws_size,
                              hipStream_t stream) {
    const int*   tokens  = (const int*)d_in[0];
    const float* embed_w = (const float*)d_in[1];
    const float* norm_w  = (const float*)d_in[2];
    const float* in_w    = (const float*)d_in[3];
    const float* in_b    = (const float*)d_in[4];
    const float* out_w   = (const float*)d_in[5];
    const float* out_b   = (const float*)d_in[6];
    const float* head_w  = (const float*)d_in[7];
    const float* head_b  = (const float*)d_in[8];
    float* logits = (float*)d_out;

    char* w = (char*)d_ws;
    unsigned short* a_buf  = (unsigned short*)w;                    // 32 MiB
    unsigned short* bx_buf = (unsigned short*)(w + 33554432);       // 32 MiB
    unsigned short* c_buf  = (unsigned short*)(w + 67108864);       // 32 MiB
    unsigned short* W2T    = (unsigned short*)(w + 100663296);      // 512 KiB
    float*          E_head = (float*)(w + 101711872);               // 16 KiB
    float*          part   = (float*)(w + 102760448);               // 8 MiB
    unsigned short* y      = (unsigned short*)(w + 134217728);      // 32 MiB
    unsigned short* in_wT  = (unsigned short*)(w + 167772160);      // 32 MiB
    unsigned short* xn     = (unsigned short*)(w + 201326592);      // 8 MiB
    float* chunkA = (float*)(w + 209715200);
    float* chunkH = chunkA + 8192 * NCHUNK;
    float* carry  = chunkH + 8192 * NCHUNK;

    hipLaunchKernelGGL(fused_pre, dim3(16384 + 4096 + 1024 + VOCAB + 1), dim3(256), 0, stream,
                       tokens, embed_w, norm_w, in_w, out_w, head_w, out_b, head_b,
                       in_wT, xn, W2T, E_head);
    hipLaunchKernelGGL(gemm_in_mfma, dim3(1024), dim3(512), 131072, stream,
                       xn, in_wT, in_b, a_buf, bx_buf, c_buf);
    hipLaunchKernelGGL(scan_phase1, dim3(512), dim3(256), 0, stream,
                       a_buf, bx_buf, chunkA, chunkH);
    hipLaunchKernelGGL(scan_phase2, dim3(32), dim3(256), 0, stream,
                       chunkA, chunkH, carry);
    hipLaunchKernelGGL(scan_phase3, dim3(512), dim3(256), 0, stream,
                       a_buf, bx_buf, c_buf, carry, y);
    hipLaunchKernelGGL(logits_gemm, dim3(256), dim3(256), 36864, stream,
                       y, W2T, part);
    hipLaunchKernelGGL(logits_reduce, dim3(MTOK), dim3(64), 0, stream,
                       part, E_head, tokens, logits);
}

// Round 19
// 276.529 us; speedup vs baseline: 1.1188x; 1.0425x over previous
//
#include <hip/hip_runtime.h>
#include <math.h>

#define HID   1024
#define STT   4096
#define MTOK  4096   // B*L
#define LSEQ  2048
#define NCHUNK 64
#define CHUNK  32
#define VOCAB  62

typedef __attribute__((ext_vector_type(8))) short short8v;
typedef __attribute__((ext_vector_type(4))) float float4v;

typedef const __attribute__((address_space(1))) void* gptr_t;
typedef __attribute__((address_space(3))) void* lptr_t;

__device__ __forceinline__ float sigmoidf_(float x) {
    return 1.0f / (1.0f + __expf(-x));
}
__device__ __forceinline__ unsigned short f2bf(float f) {
    unsigned int u = __float_as_uint(f);
    unsigned int r = (u + 0x7fffu + ((u >> 16) & 1u)) >> 16;
    return (unsigned short)r;
}
__device__ __forceinline__ float bf2f(unsigned short b) {
    return __uint_as_float(((unsigned int)b) << 16);
}

// ---------------- fused prologue (block-range partitioned) ----------------
// blocks 0..16383      : in_w [1024][16384] -> in_wT [16384][1024] bf16
// blocks 16384..20479  : embed gather + RMSNorm -> xn bf16
// blocks 20480..21503  : W2T = (out_w@head_w)^T bf16 [64][4096]
// blocks 21504..21566  : E_head rows (62 embed rows + bias2 row)
__global__ __launch_bounds__(256) void fused_pre(
    const int* __restrict__ tokens, const float* __restrict__ embed_w,
    const float* __restrict__ norm_w, const float* __restrict__ in_w,
    const float* __restrict__ out_w, const float* __restrict__ head_w,
    const float* __restrict__ out_b, const float* __restrict__ head_b,
    unsigned short* __restrict__ in_wT, unsigned short* __restrict__ xn,
    unsigned short* __restrict__ W2T, float* __restrict__ E_head)
{
    __shared__ float sh[1056];   // transpose tile 32x33 / red[4][4][64] overlay
    int bid = blockIdx.x;
    int tid = threadIdx.x;
    if (bid < 16384) {
        float (*tile)[33] = (float (*)[33])sh;
        int c0 = (bid & 511) * 32, r0 = (bid >> 9) * 32;
        int r = tid >> 3, c4 = (tid & 7) << 2;
        float4 v = *(const float4*)(in_w + (size_t)(r0 + r) * 16384 + c0 + c4);
        tile[r][c4 + 0] = v.x; tile[r][c4 + 1] = v.y;
        tile[r][c4 + 2] = v.z; tile[r][c4 + 3] = v.w;
        __syncthreads();
        int oc = tid >> 3;
        int orr = (tid & 7) << 2;
        ushort4 o;
        o.x = f2bf(tile[orr + 0][oc]); o.y = f2bf(tile[orr + 1][oc]);
        o.z = f2bf(tile[orr + 2][oc]); o.w = f2bf(tile[orr + 3][oc]);
        *(ushort4*)(in_wT + (size_t)(c0 + oc) * 1024 + r0 + orr) = o;
    } else if (bid < 20480) {
        int m = bid - 16384;
        int tok = tokens[m];
        float4 x = ((const float4*)(embed_w + (size_t)tok * HID))[tid];
        float ss = x.x * x.x + x.y * x.y + x.z * x.z + x.w * x.w;
        for (int off = 32; off > 0; off >>= 1) ss += __shfl_down(ss, off);
        if ((tid & 63) == 0) sh[tid >> 6] = ss;
        __syncthreads();
        float tot = sh[0] + sh[1] + sh[2] + sh[3];
        float scale = rsqrtf(tot / (float)HID + 1e-6f);
        float4 w4 = ((const float4*)norm_w)[tid];
        ushort4 o;
        o.x = f2bf(x.x * scale * w4.x); o.y = f2bf(x.y * scale * w4.y);
        o.z = f2bf(x.z * scale * w4.z); o.w = f2bf(x.w * scale * w4.w);
        *(ushort4*)(xn + (size_t)m * HID + (tid << 2)) = o;
    } else if (bid < 21504) {
        float (*red)[4][64] = (float (*)[4][64])sh;
        int jc = tid >> 6, n = tid & 63;
        bool act = n < VOCAB;
        int k0 = (bid - 20480) * 4;
        float a[4] = {0.f, 0.f, 0.f, 0.f};
        int j0 = jc * 256;
        const float* w0 = out_w + (size_t)(k0 + 0) * HID;
        const float* w1 = out_w + (size_t)(k0 + 1) * HID;
        const float* w2 = out_w + (size_t)(k0 + 2) * HID;
        const float* w3 = out_w + (size_t)(k0 + 3) * HID;
        #pragma unroll 4
        for (int j = j0; j < j0 + 256; j++) {
            float h = act ? head_w[(size_t)j * VOCAB + n] : 0.f;
            a[0] = fmaf(w0[j], h, a[0]);
            a[1] = fmaf(w1[j], h, a[1]);
            a[2] = fmaf(w2[j], h, a[2]);
            a[3] = fmaf(w3[j], h, a[3]);
        }
        #pragma unroll
        for (int i = 0; i < 4; i++) red[jc][i][n] = a[i];
        __syncthreads();
        if (jc == 0) {
            #pragma unroll
            for (int i = 0; i < 4; i++) {
                float s = red[0][i][n] + red[1][i][n] + red[2][i][n] + red[3][i][n];
                W2T[(size_t)n * STT + k0 + i] = f2bf(s);
            }
        }
    } else {
        float (*red)[4][64] = (float (*)[4][64])sh;
        int jc = tid >> 6, n = tid & 63;
        bool act = n < VOCAB;
        int t = bid - 21504;
        const float* src = (t < VOCAB) ? (embed_w + (size_t)t * HID) : out_b;
        float acc = 0.f;
        if (act) {
            int j0 = jc * 256;
            #pragma unroll 4
            for (int j = j0; j < j0 + 256; j++)
                acc = fmaf(src[j], head_w[(size_t)j * VOCAB + n], acc);
        }
        red[jc][0][n] = acc;
        __syncthreads();
        if (tid < 64) {
            float s = red[0][0][n] + red[1][0][n] + red[2][0][n] + red[3][0][n];
            if (t == VOCAB && act) s += head_b[n];
            E_head[t * 64 + n] = s;
        }
    }
}

// ---------------- MFMA GEMM 1 + fused gates + fused chunk-scan ----------------
// 256 rows x (4 gates x 64 s-cols), BK=64, 8 waves, 2 LDS bufs, 4-phase
// counted-vmcnt schedule, conflict-free chunk swizzle, XCD cell swizzle.
// Epilogue additionally computes per-chunk scan affine (A,H) via 2-step
// __shfl scan over lk (chunk = 32 consecutive tokens = 2 mf-frags), using the
// bf16-ROUNDED gate values (bit-identical to the old scan_phase1 semantics).
__global__ __launch_bounds__(512, 2) void gemm_in_mfma(
    const unsigned short* __restrict__ A, const unsigned short* __restrict__ B,
    const float* __restrict__ bias,
    unsigned short* __restrict__ a_out, unsigned short* __restrict__ bx_out,
    unsigned short* __restrict__ c_out,
    float* __restrict__ chunkA, float* __restrict__ chunkH)
{
    extern __shared__ unsigned short lds[];   // 2 bufs * 32768 shorts = 128 KiB
    int tid = threadIdx.x;
    int wid = tid >> 6, lane = tid & 63;
    int wg = blockIdx.x;
    int xcd = wg & 7, loc = wg >> 3;
    int by = ((xcd >> 1) << 2) + (loc & 3);   // 0..15  m-tile
    int bx = ((xcd & 1) << 5) + (loc >> 2);   // 0..63  s-slab
    int m0 = by * 256, s0 = bx * 64;
    int wm = wid >> 2, wn = wid & 3;
    int lr = lane & 15, lk = lane >> 4;

    int cb0 = wid * 64, cb1 = 512 + wid * 64;
    int p0 = cb0 + lane, p1 = cb1 + lane;
    int row0 = p0 >> 2, ks0 = (p0 & 3) ^ ((row0 >> 1) & 3);
    int row1 = p1 >> 2, ks1 = (p1 & 3) ^ ((row1 >> 1) & 3);
    int arow0 = m0 + row0, arow1 = m0 + row1;
    int brow0 = ((row0 >> 6) << 12) + s0 + (row0 & 63);
    int brow1 = ((row1 >> 6) << 12) + s0 + (row1 & 63);

#define SHALF(grow0, grow1, b, which, kt, kk) do {                               \
    unsigned short* _d = lds + (b) * 32768 + (which) * 16384 + (kk) * 8192;      \
    __builtin_amdgcn_global_load_lds(                                            \
        (gptr_t)(const void*)(((which) ? B : A) + (size_t)(grow0) * 1024 +       \
                              (kt) * 64 + (kk) * 32 + ks0 * 8),                  \
        (lptr_t)(void*)(_d + (size_t)cb0 * 8), 16, 0, 0);                        \
    __builtin_amdgcn_global_load_lds(                                            \
        (gptr_t)(const void*)(((which) ? B : A) + (size_t)(grow1) * 1024 +       \
                              (kt) * 64 + (kk) * 32 + ks1 * 8),                  \
        (lptr_t)(void*)(_d + (size_t)cb1 * 8), 16, 0, 0);                        \
} while (0)

    int ksw = lk ^ ((lr >> 1) & 3);

#define RD_A(b, kk, mf) \
    (*(const short8v*)&lds[(b) * 32768 + (kk) * 8192 + \
        (((wm * 128 + (mf) * 16 + lr) << 2) + ksw) * 8])
#define RD_B(b, kk, nf) \
    (*(const short8v*)&lds[(b) * 32768 + 16384 + (kk) * 8192 + \
        ((((nf) * 64 + wn * 16 + lr) << 2) + ksw) * 8])

#define MFMA8x2(AF, B0, B1, n0i, n1i) do {                                       \
    __builtin_amdgcn_s_setprio(1);                                               \
    _Pragma("unroll")                                                            \
    for (int mf = 0; mf < 8; mf++) {                                             \
        acc[mf][n0i] = __builtin_amdgcn_mfma_f32_16x16x32_bf16(                  \
            (AF)[mf], (B0), acc[mf][n0i], 0, 0, 0);                              \
        acc[mf][n1i] = __builtin_amdgcn_mfma_f32_16x16x32_bf16(                  \
            (AF)[mf], (B1), acc[mf][n1i], 0, 0, 0);                              \
    }                                                                            \
    __builtin_amdgcn_s_setprio(0);                                               \
} while (0)

#define BAR_IN()  do { __builtin_amdgcn_s_barrier();                              \
    asm volatile("s_waitcnt lgkmcnt(0)" ::: "memory");                           \
    __builtin_amdgcn_sched_barrier(0); } while (0)
#define BAR_OUT() do { asm volatile("" ::: "memory");                             \
    __builtin_amdgcn_s_barrier(); } while (0)

    float4v acc[8][4];
    float4v z = {0.f, 0.f, 0.f, 0.f};
    #pragma unroll
    for (int i = 0; i < 8; i++)
        #pragma unroll
        for (int j = 0; j < 4; j++) acc[i][j] = z;

    SHALF(arow0, arow1, 0, 0, 0, 0); SHALF(brow0, brow1, 0, 1, 0, 0);
    SHALF(arow0, arow1, 0, 0, 0, 1); SHALF(brow0, brow1, 0, 1, 0, 1);
    asm volatile("s_waitcnt vmcnt(0)" ::: "memory");
    __builtin_amdgcn_s_barrier();

    short8v af[8], bf0, bf1;

    for (int kt = 0; kt < 16; ++kt) {
        int cur = kt & 1, nxt = cur ^ 1;
        int ktn = kt < 15 ? kt + 1 : 15;
        #pragma unroll
        for (int mf = 0; mf < 8; mf++) af[mf] = RD_A(cur, 0, mf);
        bf0 = RD_B(cur, 0, 0); bf1 = RD_B(cur, 0, 1);
        asm volatile("s_waitcnt vmcnt(4)" ::: "memory");
        SHALF(arow0, arow1, nxt, 0, ktn, 0);
        BAR_IN();
        MFMA8x2(af, bf0, bf1, 0, 1);
        BAR_OUT();
        bf0 = RD_B(cur, 0, 2); bf1 = RD_B(cur, 0, 3);
        SHALF(brow0, brow1, nxt, 1, ktn, 0);
        BAR_IN();
        MFMA8x2(af, bf0, bf1, 2, 3);
        BAR_OUT();
        #pragma unroll
        for (int mf = 0; mf < 8; mf++) af[mf] = RD_A(cur, 1, mf);
        bf0 = RD_B(cur, 1, 0); bf1 = RD_B(cur, 1, 1);
        asm volatile("s_waitcnt vmcnt(4)" ::: "memory");
        SHALF(arow0, arow1, nxt, 0, ktn, 1);
        BAR_IN();
        MFMA8x2(af, bf0, bf1, 0, 1);
        BAR_OUT();
        bf0 = RD_B(cur, 1, 2); bf1 = RD_B(cur, 1, 3);
        SHALF(brow0, brow1, nxt, 1, ktn, 1);
        BAR_IN();
        MFMA8x2(af, bf0, bf1, 2, 3);
        BAR_OUT();
    }

    // ---- fused-gate + fused chunk-scan epilogue ----
    int s = s0 + wn * 16 + lr;
    float b_xg = bias[s];
    float b_a  = bias[4096 + s];
    float b_b  = bias[8192 + s];
    float b_c  = bias[12288 + s];
    int rbase = lk << 2;
    int bb = m0 >> 11;                 // batch index
    int t0 = m0 & 2047;                // token offset within batch
    int ch = bb * STT + s;             // channel index (matches scan2/3)

    #pragma unroll
    for (int cc = 0; cc < 4; cc++) {   // chunk cc within wave's 128 rows
        float Afr[2], Hfr[2];
        #pragma unroll
        for (int e = 0; e < 2; e++) {
            int mf = cc * 2 + e;
            float Al = 1.f, Hl = 0.f;
            #pragma unroll
            for (int q = 0; q < 4; q++) {
                int m = m0 + wm * 128 + mf * 16 + rbase + q;
                size_t idx = (size_t)m * STT + s;
                float xg = acc[mf][0][q] + b_xg;
                float av = sigmoidf_(acc[mf][1][q] + b_a);
                float bxv = sigmoidf_(acc[mf][2][q] + b_b) * xg;
                float cv = sigmoidf_(acc[mf][3][q] + b_c);
                unsigned short au = f2bf(av), bu = f2bf(bxv);
                a_out[idx]  = au;
                bx_out[idx] = bu;
                c_out[idx]  = f2bf(cv);
                float ar = bf2f(au), br = bf2f(bu);   // rounded (match old scan1)
                Hl = fmaf(ar, Hl, br);
                Al = ar * Al;
            }
            // inclusive affine scan over lk (lane distance 16, 32)
            #pragma unroll
            for (int d = 1; d <= 2; d <<= 1) {
                float Ap = __shfl(Al, lane - (d << 4));
                float Hp = __shfl(Hl, lane - (d << 4));
                if (lk >= d) { Hl = fmaf(Al, Hp, Hl); Al = Al * Ap; }
            }
            Afr[e] = Al; Hfr[e] = Hl;
        }
        if (lk == 3) {
            float Ac = Afr[1] * Afr[0];
            float Hc = fmaf(Afr[1], Hfr[0], Hfr[1]);
            int qg = (t0 >> 5) + wm * 4 + cc;        // global chunk in sequence
            chunkA[ch * NCHUNK + qg] = Ac;
            chunkH[ch * NCHUNK + qg] = Hc;
        }
    }
#undef SHALF
#undef RD_A
#undef RD_B
#undef MFMA8x2
#undef BAR_IN
#undef BAR_OUT
}

// ---------------- logits GEMM: part[s] = y[mtile] @ W2T^T (K-slice) --------
__global__ __launch_bounds__(256, 3) void logits_gemm(
    const unsigned short* __restrict__ Y, const unsigned short* __restrict__ W2T,
    float* __restrict__ part)
{
    extern __shared__ unsigned short lds[];   // 3 bufs * 6144 shorts = 36 KiB
    int tid = threadIdx.x;
    int wid = tid >> 6, lane = tid & 63;
    int wg = blockIdx.x;
    int m0 = (wg & 31) * 128;
    int slice = wg >> 5;
    int ks0 = slice * 512;
    int wm = wid >> 1, wn = wid & 1;
    int lr = lane & 15, lk = lane >> 4;

    auto stage = [&](int b, int kt) {
        unsigned short* As = lds + b * 6144;
        unsigned short* Bs = As + 4096;
        #pragma unroll
        for (int i = 0; i < 2; i++) {
            int cb = i * 256 + wid * 64;
            int p = cb + lane;
            int row = p >> 2;
            int ks = (p & 3) ^ ((row >> 1) & 3);
            __builtin_amdgcn_global_load_lds(
                (gptr_t)(const void*)(Y + (size_t)(m0 + row) * STT + kt + ks * 8),
                (lptr_t)(void*)(As + (size_t)cb * 8), 16, 0, 0);
        }
        {
            int cb = wid * 64;
            int p = cb + lane;
            int row = p >> 2;
            int ks = (p & 3) ^ ((row >> 1) & 3);
            __builtin_amdgcn_global_load_lds(
                (gptr_t)(const void*)(W2T + (size_t)row * STT + kt + ks * 8),
                (lptr_t)(void*)(Bs + (size_t)cb * 8), 16, 0, 0);
        }
    };

    float4v acc[4][2];
    float4v z = {0.f, 0.f, 0.f, 0.f};
    #pragma unroll
    for (int i = 0; i < 4; i++) { acc[i][0] = z; acc[i][1] = z; }

    const int nt = 16;
    stage(0, ks0); stage(1, ks0 + 32);

    int ksw = lk ^ ((lr >> 1) & 3);

    for (int t = 0; t < nt; ++t) {
        if (t + 2 < nt) stage((t + 2) % 3, ks0 + (t + 2) * 32);
        if (t + 2 < nt)      asm volatile("s_waitcnt vmcnt(6)" ::: "memory");
        else if (t + 1 < nt) asm volatile("s_waitcnt vmcnt(3)" ::: "memory");
        else                 asm volatile("s_waitcnt vmcnt(0)" ::: "memory");
        __builtin_amdgcn_s_barrier();
        asm volatile("" ::: "memory");
        const unsigned short* As = lds + (t % 3) * 6144;
        const unsigned short* Bs = As + 4096;
        short8v af[4], bfr[2];
        #pragma unroll
        for (int f = 0; f < 4; f++)
            af[f] = *(const short8v*)&As[(((wm * 64 + f * 16 + lr) << 2) + ksw) * 8];
        #pragma unroll
        for (int g = 0; g < 2; g++)
            bfr[g] = *(const short8v*)&Bs[(((wn * 32 + g * 16 + lr) << 2) + ksw) * 8];
        __builtin_amdgcn_s_setprio(1);
        #pragma unroll
        for (int f = 0; f < 4; f++)
            #pragma unroll
            for (int g = 0; g < 2; g++)
                acc[f][g] = __builtin_amdgcn_mfma_f32_16x16x32_bf16(
                    af[f], bfr[g], acc[f][g], 0, 0, 0);
        __builtin_amdgcn_s_setprio(0);
        asm volatile("" ::: "memory");
        __builtin_amdgcn_s_barrier();
    }

    float* pb = part + (size_t)slice * MTOK * 64;
    int rbase = lk << 2;
    #pragma unroll
    for (int f = 0; f < 4; f++)
        #pragma unroll
        for (int g = 0; g < 2; g++) {
            int n = wn * 32 + g * 16 + lr;
            #pragma unroll
            for (int q = 0; q < 4; q++) {
                int m = m0 + wm * 64 + f * 16 + rbase + q;
                pb[(size_t)m * 64 + n] = acc[f][g][q];
            }
        }
}

// ---------------- logits reduce: sum 8 partials + E_head[tok] + bias2 -------
__global__ __launch_bounds__(64) void logits_reduce(
    const float* __restrict__ part, const float* __restrict__ E_head,
    const int* __restrict__ tokens, float* __restrict__ logits)
{
    int m = blockIdx.x;
    int n = threadIdx.x;
    if (n >= VOCAB) return;
    int tok = tokens[m];
    float s = E_head[tok * 64 + n] + E_head[VOCAB * 64 + n];
    #pragma unroll
    for (int sl = 0; sl < 8; sl++)
        s += part[(size_t)sl * MTOK * 64 + (size_t)m * 64 + n];
    logits[(size_t)m * VOCAB + n] = s;
}

__global__ __launch_bounds__(256) void scan_phase2(
    const float* __restrict__ chunkA, const float* __restrict__ chunkH,
    float* __restrict__ carry)
{
    int ch = blockIdx.x * 256 + threadIdx.x;
    float c = 0.f;
    for (int q = 0; q < NCHUNK; q++) {
        carry[ch * NCHUNK + q] = c;
        c = fmaf(chunkA[ch * NCHUNK + q], c, chunkH[ch * NCHUNK + q]);
    }
}

// ---------------- scan phase 3 (frozen) ----------
__global__ __launch_bounds__(256) void scan_phase3(
    const unsigned short* __restrict__ a_buf, const unsigned short* __restrict__ bx_buf,
    const unsigned short* __restrict__ c_buf, const float* __restrict__ carry,
    unsigned short* __restrict__ y)
{
    int bid = blockIdx.x;
    int sg = bid & 3, q = (bid >> 2) & 63, b = bid >> 8;
    int s0 = sg * 1024 + threadIdx.x * 4;
    float h[4];
    #pragma unroll
    for (int j = 0; j < 4; j++)
        h[j] = carry[(b * STT + s0 + j) * NCHUNK + q];
    size_t base = (size_t)(b * LSEQ + q * CHUNK) * STT + s0;
    const unsigned short* ap = a_buf + base;
    const unsigned short* bp = bx_buf + base;
    const unsigned short* cp = c_buf + base;
    unsigned short* yp = y + base;
    for (int t = 0; t < CHUNK; t++) {
        ushort4 Av = *(const ushort4*)ap;
        ushort4 Bv = *(const ushort4*)bp;
        ushort4 Cv = *(const ushort4*)cp;
        const unsigned short* avp = (const unsigned short*)&Av;
        const unsigned short* bvp = (const unsigned short*)&Bv;
        const unsigned short* cvp = (const unsigned short*)&Cv;
        ushort4 o;
        unsigned short* op = (unsigned short*)&o;
        #pragma unroll
        for (int j = 0; j < 4; j++) {
            h[j] = fmaf(bf2f(avp[j]), h[j], bf2f(bvp[j]));
            op[j] = f2bf(bf2f(cvp[j]) * h[j]);
        }
        *(ushort4*)yp = o;
        ap += STT; bp += STT; cp += STT; yp += STT;
    }
}

extern "C" void kernel_launch(void* const* d_in, const int* in_sizes, int n_in,
                              void* d_out, int out_size, void* d_ws, size_t ws_size,
                              hipStream_t stream) {
    const int*   tokens  = (const int*)d_in[0];
    const float* embed_w = (const float*)d_in[1];
    const float* norm_w  = (const float*)d_in[2];
    const float* in_w    = (const float*)d_in[3];
    const float* in_b    = (const float*)d_in[4];
    const float* out_w   = (const float*)d_in[5];
    const float* out_b   = (const float*)d_in[6];
    const float* head_w  = (const float*)d_in[7];
    const float* head_b  = (const float*)d_in[8];
    float* logits = (float*)d_out;

    char* w = (char*)d_ws;
    unsigned short* a_buf  = (unsigned short*)w;                    // 32 MiB
    unsigned short* bx_buf = (unsigned short*)(w + 33554432);       // 32 MiB
    unsigned short* c_buf  = (unsigned short*)(w + 67108864);       // 32 MiB
    unsigned short* W2T    = (unsigned short*)(w + 100663296);      // 512 KiB
    float*          E_head = (float*)(w + 101711872);               // 16 KiB
    float*          part   = (float*)(w + 102760448);               // 8 MiB
    unsigned short* y      = (unsigned short*)(w + 134217728);      // 32 MiB
    unsigned short* in_wT  = (unsigned short*)(w + 167772160);      // 32 MiB
    unsigned short* xn     = (unsigned short*)(w + 201326592);      // 8 MiB
    float* chunkA = (float*)(w + 209715200);
    float* chunkH = chunkA + 8192 * NCHUNK;
    float* carry  = chunkH + 8192 * NCHUNK;

    hipLaunchKernelGGL(fused_pre, dim3(16384 + 4096 + 1024 + VOCAB + 1), dim3(256), 0, stream,
                       tokens, embed_w, norm_w, in_w, out_w, head_w, out_b, head_b,
                       in_wT, xn, W2T, E_head);
    hipLaunchKernelGGL(gemm_in_mfma, dim3(1024), dim3(512), 131072, stream,
                       xn, in_wT, in_b, a_buf, bx_buf, c_buf, chunkA, chunkH);
    hipLaunchKernelGGL(scan_phase2, dim3(32), dim3(256), 0, stream,
                       chunkA, chunkH, carry);
    hipLaunchKernelGGL(scan_phase3, dim3(512), dim3(256), 0, stream,
                       a_buf, bx_buf, c_buf, carry, y);
    hipLaunchKernelGGL(logits_gemm, dim3(256), dim3(256), 36864, stream,
                       y, W2T, part);
    hipLaunchKernelGGL(logits_reduce, dim3(MTOK), dim3(64), 0, stream,
                       part, E_head, tokens, logits);
}

// Round 20
// 266.801 us; speedup vs baseline: 1.1596x; 1.0365x over previous
//
#include <hip/hip_runtime.h>
#include <math.h>

#define HID   1024
#define STT   4096
#define MTOK  4096   // B*L
#define LSEQ  2048
#define NCHUNK 64
#define CHUNK  32
#define VOCAB  62

typedef __attribute__((ext_vector_type(8))) short short8v;
typedef __attribute__((ext_vector_type(4))) float float4v;

typedef const __attribute__((address_space(1))) void* gptr_t;
typedef __attribute__((address_space(3))) void* lptr_t;

__device__ __forceinline__ float sigmoidf_(float x) {
    return 1.0f / (1.0f + __expf(-x));
}
__device__ __forceinline__ unsigned short f2bf(float f) {
    unsigned int u = __float_as_uint(f);
    unsigned int r = (u + 0x7fffu + ((u >> 16) & 1u)) >> 16;
    return (unsigned short)r;
}
__device__ __forceinline__ float bf2f(unsigned short b) {
    return __uint_as_float(((unsigned int)b) << 16);
}

// ---------------- fused prologue (block-range partitioned) ----------------
__global__ __launch_bounds__(256) void fused_pre(
    const int* __restrict__ tokens, const float* __restrict__ embed_w,
    const float* __restrict__ norm_w, const float* __restrict__ in_w,
    const float* __restrict__ out_w, const float* __restrict__ head_w,
    const float* __restrict__ out_b, const float* __restrict__ head_b,
    unsigned short* __restrict__ in_wT, unsigned short* __restrict__ xn,
    unsigned short* __restrict__ W2T, float* __restrict__ E_head)
{
    __shared__ float sh[1056];
    int bid = blockIdx.x;
    int tid = threadIdx.x;
    if (bid < 16384) {
        float (*tile)[33] = (float (*)[33])sh;
        int c0 = (bid & 511) * 32, r0 = (bid >> 9) * 32;
        int r = tid >> 3, c4 = (tid & 7) << 2;
        float4 v = *(const float4*)(in_w + (size_t)(r0 + r) * 16384 + c0 + c4);
        tile[r][c4 + 0] = v.x; tile[r][c4 + 1] = v.y;
        tile[r][c4 + 2] = v.z; tile[r][c4 + 3] = v.w;
        __syncthreads();
        int oc = tid >> 3;
        int orr = (tid & 7) << 2;
        ushort4 o;
        o.x = f2bf(tile[orr + 0][oc]); o.y = f2bf(tile[orr + 1][oc]);
        o.z = f2bf(tile[orr + 2][oc]); o.w = f2bf(tile[orr + 3][oc]);
        *(ushort4*)(in_wT + (size_t)(c0 + oc) * 1024 + r0 + orr) = o;
    } else if (bid < 20480) {
        int m = bid - 16384;
        int tok = tokens[m];
        float4 x = ((const float4*)(embed_w + (size_t)tok * HID))[tid];
        float ss = x.x * x.x + x.y * x.y + x.z * x.z + x.w * x.w;
        for (int off = 32; off > 0; off >>= 1) ss += __shfl_down(ss, off);
        if ((tid & 63) == 0) sh[tid >> 6] = ss;
        __syncthreads();
        float tot = sh[0] + sh[1] + sh[2] + sh[3];
        float scale = rsqrtf(tot / (float)HID + 1e-6f);
        float4 w4 = ((const float4*)norm_w)[tid];
        ushort4 o;
        o.x = f2bf(x.x * scale * w4.x); o.y = f2bf(x.y * scale * w4.y);
        o.z = f2bf(x.z * scale * w4.z); o.w = f2bf(x.w * scale * w4.w);
        *(ushort4*)(xn + (size_t)m * HID + (tid << 2)) = o;
    } else if (bid < 21504) {
        float (*red)[4][64] = (float (*)[4][64])sh;
        int jc = tid >> 6, n = tid & 63;
        bool act = n < VOCAB;
        int k0 = (bid - 20480) * 4;
        float a[4] = {0.f, 0.f, 0.f, 0.f};
        int j0 = jc * 256;
        const float* w0 = out_w + (size_t)(k0 + 0) * HID;
        const float* w1 = out_w + (size_t)(k0 + 1) * HID;
        const float* w2 = out_w + (size_t)(k0 + 2) * HID;
        const float* w3 = out_w + (size_t)(k0 + 3) * HID;
        #pragma unroll 4
        for (int j = j0; j < j0 + 256; j++) {
            float h = act ? head_w[(size_t)j * VOCAB + n] : 0.f;
            a[0] = fmaf(w0[j], h, a[0]);
            a[1] = fmaf(w1[j], h, a[1]);
            a[2] = fmaf(w2[j], h, a[2]);
            a[3] = fmaf(w3[j], h, a[3]);
        }
        #pragma unroll
        for (int i = 0; i < 4; i++) red[jc][i][n] = a[i];
        __syncthreads();
        if (jc == 0) {
            #pragma unroll
            for (int i = 0; i < 4; i++) {
                float s = red[0][i][n] + red[1][i][n] + red[2][i][n] + red[3][i][n];
                W2T[(size_t)n * STT + k0 + i] = f2bf(s);
            }
        }
    } else {
        float (*red)[4][64] = (float (*)[4][64])sh;
        int jc = tid >> 6, n = tid & 63;
        bool act = n < VOCAB;
        int t = bid - 21504;
        const float* src = (t < VOCAB) ? (embed_w + (size_t)t * HID) : out_b;
        float acc = 0.f;
        if (act) {
            int j0 = jc * 256;
            #pragma unroll 4
            for (int j = j0; j < j0 + 256; j++)
                acc = fmaf(src[j], head_w[(size_t)j * VOCAB + n], acc);
        }
        red[jc][0][n] = acc;
        __syncthreads();
        if (tid < 64) {
            float s = red[0][0][n] + red[1][0][n] + red[2][0][n] + red[3][0][n];
            if (t == VOCAB && act) s += head_b[n];
            E_head[t * 64 + n] = s;
        }
    }
}

// ---------------- MFMA GEMM 1 + fused gates + fused chunk-scan (frozen) ------
__global__ __launch_bounds__(512, 2) void gemm_in_mfma(
    const unsigned short* __restrict__ A, const unsigned short* __restrict__ B,
    const float* __restrict__ bias,
    unsigned short* __restrict__ a_out, unsigned short* __restrict__ bx_out,
    unsigned short* __restrict__ c_out,
    float* __restrict__ chunkA, float* __restrict__ chunkH)
{
    extern __shared__ unsigned short lds[];   // 2 bufs * 32768 shorts = 128 KiB
    int tid = threadIdx.x;
    int wid = tid >> 6, lane = tid & 63;
    int wg = blockIdx.x;
    int xcd = wg & 7, loc = wg >> 3;
    int by = ((xcd >> 1) << 2) + (loc & 3);
    int bx = ((xcd & 1) << 5) + (loc >> 2);
    int m0 = by * 256, s0 = bx * 64;
    int wm = wid >> 2, wn = wid & 3;
    int lr = lane & 15, lk = lane >> 4;

    int cb0 = wid * 64, cb1 = 512 + wid * 64;
    int p0 = cb0 + lane, p1 = cb1 + lane;
    int row0 = p0 >> 2, ks0 = (p0 & 3) ^ ((row0 >> 1) & 3);
    int row1 = p1 >> 2, ks1 = (p1 & 3) ^ ((row1 >> 1) & 3);
    int arow0 = m0 + row0, arow1 = m0 + row1;
    int brow0 = ((row0 >> 6) << 12) + s0 + (row0 & 63);
    int brow1 = ((row1 >> 6) << 12) + s0 + (row1 & 63);

#define SHALF(grow0, grow1, b, which, kt, kk) do {                               \
    unsigned short* _d = lds + (b) * 32768 + (which) * 16384 + (kk) * 8192;      \
    __builtin_amdgcn_global_load_lds(                                            \
        (gptr_t)(const void*)(((which) ? B : A) + (size_t)(grow0) * 1024 +       \
                              (kt) * 64 + (kk) * 32 + ks0 * 8),                  \
        (lptr_t)(void*)(_d + (size_t)cb0 * 8), 16, 0, 0);                        \
    __builtin_amdgcn_global_load_lds(                                            \
        (gptr_t)(const void*)(((which) ? B : A) + (size_t)(grow1) * 1024 +       \
                              (kt) * 64 + (kk) * 32 + ks1 * 8),                  \
        (lptr_t)(void*)(_d + (size_t)cb1 * 8), 16, 0, 0);                        \
} while (0)

    int ksw = lk ^ ((lr >> 1) & 3);

#define RD_A(b, kk, mf) \
    (*(const short8v*)&lds[(b) * 32768 + (kk) * 8192 + \
        (((wm * 128 + (mf) * 16 + lr) << 2) + ksw) * 8])
#define RD_B(b, kk, nf) \
    (*(const short8v*)&lds[(b) * 32768 + 16384 + (kk) * 8192 + \
        ((((nf) * 64 + wn * 16 + lr) << 2) + ksw) * 8])

#define MFMA8x2(AF, B0, B1, n0i, n1i) do {                                       \
    __builtin_amdgcn_s_setprio(1);                                               \
    _Pragma("unroll")                                                            \
    for (int mf = 0; mf < 8; mf++) {                                             \
        acc[mf][n0i] = __builtin_amdgcn_mfma_f32_16x16x32_bf16(                  \
            (AF)[mf], (B0), acc[mf][n0i], 0, 0, 0);                              \
        acc[mf][n1i] = __builtin_amdgcn_mfma_f32_16x16x32_bf16(                  \
            (AF)[mf], (B1), acc[mf][n1i], 0, 0, 0);                              \
    }                                                                            \
    __builtin_amdgcn_s_setprio(0);                                               \
} while (0)

#define BAR_IN()  do { __builtin_amdgcn_s_barrier();                              \
    asm volatile("s_waitcnt lgkmcnt(0)" ::: "memory");                           \
    __builtin_amdgcn_sched_barrier(0); } while (0)
#define BAR_OUT() do { asm volatile("" ::: "memory");                             \
    __builtin_amdgcn_s_barrier(); } while (0)

    float4v acc[8][4];
    float4v z = {0.f, 0.f, 0.f, 0.f};
    #pragma unroll
    for (int i = 0; i < 8; i++)
        #pragma unroll
        for (int j = 0; j < 4; j++) acc[i][j] = z;

    SHALF(arow0, arow1, 0, 0, 0, 0); SHALF(brow0, brow1, 0, 1, 0, 0);
    SHALF(arow0, arow1, 0, 0, 0, 1); SHALF(brow0, brow1, 0, 1, 0, 1);
    asm volatile("s_waitcnt vmcnt(0)" ::: "memory");
    __builtin_amdgcn_s_barrier();

    short8v af[8], bf0, bf1;

    for (int kt = 0; kt < 16; ++kt) {
        int cur = kt & 1, nxt = cur ^ 1;
        int ktn = kt < 15 ? kt + 1 : 15;
        #pragma unroll
        for (int mf = 0; mf < 8; mf++) af[mf] = RD_A(cur, 0, mf);
        bf0 = RD_B(cur, 0, 0); bf1 = RD_B(cur, 0, 1);
        asm volatile("s_waitcnt vmcnt(4)" ::: "memory");
        SHALF(arow0, arow1, nxt, 0, ktn, 0);
        BAR_IN();
        MFMA8x2(af, bf0, bf1, 0, 1);
        BAR_OUT();
        bf0 = RD_B(cur, 0, 2); bf1 = RD_B(cur, 0, 3);
        SHALF(brow0, brow1, nxt, 1, ktn, 0);
        BAR_IN();
        MFMA8x2(af, bf0, bf1, 2, 3);
        BAR_OUT();
        #pragma unroll
        for (int mf = 0; mf < 8; mf++) af[mf] = RD_A(cur, 1, mf);
        bf0 = RD_B(cur, 1, 0); bf1 = RD_B(cur, 1, 1);
        asm volatile("s_waitcnt vmcnt(4)" ::: "memory");
        SHALF(arow0, arow1, nxt, 0, ktn, 1);
        BAR_IN();
        MFMA8x2(af, bf0, bf1, 0, 1);
        BAR_OUT();
        bf0 = RD_B(cur, 1, 2); bf1 = RD_B(cur, 1, 3);
        SHALF(brow0, brow1, nxt, 1, ktn, 1);
        BAR_IN();
        MFMA8x2(af, bf0, bf1, 2, 3);
        BAR_OUT();
    }

    int s = s0 + wn * 16 + lr;
    float b_xg = bias[s];
    float b_a  = bias[4096 + s];
    float b_b  = bias[8192 + s];
    float b_c  = bias[12288 + s];
    int rbase = lk << 2;
    int bb = m0 >> 11;
    int t0 = m0 & 2047;
    int ch = bb * STT + s;

    #pragma unroll
    for (int cc = 0; cc < 4; cc++) {
        float Afr[2], Hfr[2];
        #pragma unroll
        for (int e = 0; e < 2; e++) {
            int mf = cc * 2 + e;
            float Al = 1.f, Hl = 0.f;
            #pragma unroll
            for (int q = 0; q < 4; q++) {
                int m = m0 + wm * 128 + mf * 16 + rbase + q;
                size_t idx = (size_t)m * STT + s;
                float xg = acc[mf][0][q] + b_xg;
                float av = sigmoidf_(acc[mf][1][q] + b_a);
                float bxv = sigmoidf_(acc[mf][2][q] + b_b) * xg;
                float cv = sigmoidf_(acc[mf][3][q] + b_c);
                unsigned short au = f2bf(av), bu = f2bf(bxv);
                a_out[idx]  = au;
                bx_out[idx] = bu;
                c_out[idx]  = f2bf(cv);
                float ar = bf2f(au), br = bf2f(bu);
                Hl = fmaf(ar, Hl, br);
                Al = ar * Al;
            }
            #pragma unroll
            for (int d = 1; d <= 2; d <<= 1) {
                float Ap = __shfl(Al, lane - (d << 4));
                float Hp = __shfl(Hl, lane - (d << 4));
                if (lk >= d) { Hl = fmaf(Al, Hp, Hl); Al = Al * Ap; }
            }
            Afr[e] = Al; Hfr[e] = Hl;
        }
        if (lk == 3) {
            float Ac = Afr[1] * Afr[0];
            float Hc = fmaf(Afr[1], Hfr[0], Hfr[1]);
            int qg = (t0 >> 5) + wm * 4 + cc;
            chunkA[ch * NCHUNK + qg] = Ac;
            chunkH[ch * NCHUNK + qg] = Hc;
        }
    }
#undef SHALF
#undef RD_A
#undef RD_B
#undef MFMA8x2
#undef BAR_IN
#undef BAR_OUT
}

__global__ __launch_bounds__(256) void scan_phase2(
    const float* __restrict__ chunkA, const float* __restrict__ chunkH,
    float* __restrict__ carry)
{
    int ch = blockIdx.x * 256 + threadIdx.x;
    float c = 0.f;
    for (int q = 0; q < NCHUNK; q++) {
        carry[ch * NCHUNK + q] = c;
        c = fmaf(chunkA[ch * NCHUNK + q], c, chunkH[ch * NCHUNK + q]);
    }
}

// ---------------- fused scan3 + logits GEMM ----------------
// grid 256: mt = wg&31 (128-token tile = 4 chunks), sl = wg>>5 (512-ch slice).
// Per 128-ch subtile ks (4): wave w scans chunk w (carry-init per chunk, 2 ch/
// thread, uint loads), writes bf16 y into LDS tile [128][128] with XOR-chunk
// swizzle (c ^ (row&7), measured-0-conflict class); stages W2T slice via
// gload_lds with inverse-swizzled source; then 32 MFMA accumulate. y never
// touches HBM (saves 64 MB round-trip vs scan_phase3 + logits_gemm).
__global__ __launch_bounds__(256) void scan_logits(
    const unsigned short* __restrict__ a_buf, const unsigned short* __restrict__ bx_buf,
    const unsigned short* __restrict__ c_buf, const float* __restrict__ carry,
    const unsigned short* __restrict__ W2T, float* __restrict__ part)
{
    __shared__ __align__(16) unsigned short y_lds[128 * 128];   // 32 KiB
    __shared__ __align__(16) unsigned short b_lds[64 * 128];    // 16 KiB
    int tid = threadIdx.x;
    int wg = blockIdx.x;
    int mt = wg & 31, sl = wg >> 5;
    int m0 = mt * 128;
    int bb = m0 >> 11;
    int q0 = (m0 & 2047) >> 5;
    int lane = tid & 63, wid = tid >> 6;
    int lr = lane & 15, lk = lane >> 4;

    float4v acc[2][4];
    float4v z = {0.f, 0.f, 0.f, 0.f};
    #pragma unroll
    for (int e = 0; e < 2; e++)
        #pragma unroll
        for (int nf = 0; nf < 4; nf++) acc[e][nf] = z;

    for (int ks = 0; ks < 4; ++ks) {
        int sbase = sl * 512 + ks * 128;
        // ---- stage W2T subtile [64 rows][16 chunks], swizzled dest layout
        #pragma unroll
        for (int i = 0; i < 4; i++) {
            int cb = i * 256 + wid * 64;
            int p = cb + lane;
            int row = p >> 4, csw = p & 15;
            int c = csw ^ (row & 7);
            __builtin_amdgcn_global_load_lds(
                (gptr_t)(const void*)(W2T + (size_t)row * STT + sbase + c * 8),
                (lptr_t)(void*)(b_lds + (size_t)cb * 8), 16, 0, 0);
        }
        // ---- scan-compute y for 128 tokens x 128 channels
        {
            int chq = wid;                    // wave = chunk
            int s = sbase + lane * 2;         // 2 channels per thread
            int q = q0 + chq;
            size_t cidx = ((size_t)(bb * STT + s)) * NCHUNK + q;
            float h0 = carry[cidx];
            float h1 = carry[cidx + NCHUNK];
            size_t gb = (size_t)(m0 + chq * 32) * STT + s;
            const unsigned int* ap = (const unsigned int*)(a_buf + gb);
            const unsigned int* bp = (const unsigned int*)(bx_buf + gb);
            const unsigned int* cp = (const unsigned int*)(c_buf + gb);
            const int stride = STT / 2;       // uint units per token
            #pragma unroll 4
            for (int i = 0; i < 32; i++) {
                unsigned int au = ap[(size_t)i * stride];
                unsigned int bu = bp[(size_t)i * stride];
                unsigned int cu = cp[(size_t)i * stride];
                float a0 = bf2f((unsigned short)(au & 0xffff));
                float a1 = bf2f((unsigned short)(au >> 16));
                float b0 = bf2f((unsigned short)(bu & 0xffff));
                float b1 = bf2f((unsigned short)(bu >> 16));
                float c0 = bf2f((unsigned short)(cu & 0xffff));
                float c1 = bf2f((unsigned short)(cu >> 16));
                h0 = fmaf(a0, h0, b0);
                h1 = fmaf(a1, h1, b1);
                unsigned int yp = (unsigned int)f2bf(c0 * h0) |
                                  ((unsigned int)f2bf(c1 * h1) << 16);
                int row = chq * 32 + i;
                int cw = (lane >> 2) ^ (row & 7);              // swizzled chunk
                *(unsigned int*)&y_lds[row * 128 + (cw << 3) + (lane & 3) * 2] = yp;
            }
        }
        __syncthreads();
        // ---- MFMA: C[128][64] += y[128][128] x W2T[64][128]^T
        #pragma unroll
        for (int kt2 = 0; kt2 < 4; kt2++) {
            short8v af[2], bf[4];
            #pragma unroll
            for (int e = 0; e < 2; e++) {
                int row = (wid * 2 + e) * 16 + lr;
                int c = kt2 * 4 + lk;
                af[e] = *(const short8v*)&y_lds[row * 128 + ((c ^ (row & 7)) << 3)];
            }
            #pragma unroll
            for (int nf = 0; nf < 4; nf++) {
                int row = nf * 16 + lr;
                int c = kt2 * 4 + lk;
                bf[nf] = *(const short8v*)&b_lds[row * 128 + ((c ^ (row & 7)) << 3)];
            }
            __builtin_amdgcn_s_setprio(1);
            #pragma unroll
            for (int e = 0; e < 2; e++)
                #pragma unroll
                for (int nf = 0; nf < 4; nf++)
                    acc[e][nf] = __builtin_amdgcn_mfma_f32_16x16x32_bf16(
                        af[e], bf[nf], acc[e][nf], 0, 0, 0);
            __builtin_amdgcn_s_setprio(0);
        }
        __syncthreads();
    }

    float* pb = part + (size_t)sl * MTOK * 64;
    int rbase = lk << 2;
    #pragma unroll
    for (int e = 0; e < 2; e++)
        #pragma unroll
        for (int nf = 0; nf < 4; nf++) {
            int n = nf * 16 + lr;
            #pragma unroll
            for (int q = 0; q < 4; q++) {
                int m = m0 + (wid * 2 + e) * 16 + rbase + q;
                pb[(size_t)m * 64 + n] = acc[e][nf][q];
            }
        }
}

// ---------------- logits reduce: sum 8 partials + E_head[tok] + bias2 -------
__global__ __launch_bounds__(64) void logits_reduce(
    const float* __restrict__ part, const float* __restrict__ E_head,
    const int* __restrict__ tokens, float* __restrict__ logits)
{
    int m = blockIdx.x;
    int n = threadIdx.x;
    if (n >= VOCAB) return;
    int tok = tokens[m];
    float s = E_head[tok * 64 + n] + E_head[VOCAB * 64 + n];
    #pragma unroll
    for (int sl = 0; sl < 8; sl++)
        s += part[(size_t)sl * MTOK * 64 + (size_t)m * 64 + n];
    logits[(size_t)m * VOCAB + n] = s;
}

extern "C" void kernel_launch(void* const* d_in, const int* in_sizes, int n_in,
                              void* d_out, int out_size, void* d_ws, size_t ws_size,
                              hipStream_t stream) {
    const int*   tokens  = (const int*)d_in[0];
    const float* embed_w = (const float*)d_in[1];
    const float* norm_w  = (const float*)d_in[2];
    const float* in_w    = (const float*)d_in[3];
    const float* in_b    = (const float*)d_in[4];
    const float* out_w   = (const float*)d_in[5];
    const float* out_b   = (const float*)d_in[6];
    const float* head_w  = (const float*)d_in[7];
    const float* head_b  = (const float*)d_in[8];
    float* logits = (float*)d_out;

    char* w = (char*)d_ws;
    unsigned short* a_buf  = (unsigned short*)w;                    // 32 MiB
    unsigned short* bx_buf = (unsigned short*)(w + 33554432);       // 32 MiB
    unsigned short* c_buf  = (unsigned short*)(w + 67108864);       // 32 MiB
    unsigned short* W2T    = (unsigned short*)(w + 100663296);      // 512 KiB
    float*          E_head = (float*)(w + 101711872);               // 16 KiB
    float*          part   = (float*)(w + 102760448);               // 8 MiB
    unsigned short* in_wT  = (unsigned short*)(w + 167772160);      // 32 MiB
    unsigned short* xn     = (unsigned short*)(w + 201326592);      // 8 MiB
    float* chunkA = (float*)(w + 209715200);
    float* chunkH = chunkA + 8192 * NCHUNK;
    float* carry  = chunkH + 8192 * NCHUNK;

    hipLaunchKernelGGL(fused_pre, dim3(16384 + 4096 + 1024 + VOCAB + 1), dim3(256), 0, stream,
                       tokens, embed_w, norm_w, in_w, out_w, head_w, out_b, head_b,
                       in_wT, xn, W2T, E_head);
    hipLaunchKernelGGL(gemm_in_mfma, dim3(1024), dim3(512), 131072, stream,
                       xn, in_wT, in_b, a_buf, bx_buf, c_buf, chunkA, chunkH);
    hipLaunchKernelGGL(scan_phase2, dim3(32), dim3(256), 0, stream,
                       chunkA, chunkH, carry);
    hipLaunchKernelGGL(scan_logits, dim3(256), dim3(256), 0, stream,
                       a_buf, bx_buf, c_buf, carry, W2T, part);
    hipLaunchKernelGGL(logits_reduce, dim3(MTOK), dim3(64), 0, stream,
                       part, E_head, tokens, logits);
}